// Round 16
// baseline (261.594 us; speedup 1.0000x reference)
//
#include <hip/hip_runtime.h>
#include <math.h>

#define E_EDGES 65536
#define N_NODES 8192

typedef _Float16 half_t;
typedef _Float16 h8 __attribute__((ext_vector_type(8)));
typedef float f4 __attribute__((ext_vector_type(4)));

#define SSC_P 136   // padded pitch (halves): 272B rows, 16B-aligned

// W3J sparse constants (literal blocks proven vs reference through R1-R13)
#define C3f   0.57735026918962576f
#define C5f   0.44721359549995794f
#define C10f  0.31622776601683794f
#define C30f  0.18257418583505536f
#define C30x2 0.36514837167011072f
#define A235  0.23904572186687872f
#define B370  0.20701966780270626f
#define C70f  0.11952286093343936f
#define S3f   1.7320508075688772f
#define S5f   2.2360679774997896f
#define S5n  -2.2360679774997896f

// ============================================================================
// STATE (future rounds read this; history is not shown to you)
// ----------------------------------------------------------------------------
// CORRECTNESS: FLIPS = {5,13,14} (GB_FLIP) SOLVED R1-R8 — DO NOT CHANGE.
// TP: literal for blocks 0-4,6,7,9-12 (= hand formulas), 13,14 = hand*(-1);
// blocks 5,8 MUST stay table-loaded from gen_w3j output (signs not pinned).
// If absmax ever >0.5 after a TP edit: revert to R12's dense sw-table TP.
// MFMA fragment layouts (VERIFIED R12):
//   A[M=16][K=32]: lane l holds A[l&15][32ks + 8*(l>>4) + i], i=0..7
//   B[K=32][N=16]: lane l holds B[32ks + 8*(l>>4) + i][l&15]   (prep_weights)
//   C/D: row=4*(l>>4)+i, col=l&15
// PERF LOG:
//  R8: 2058 / edge 1481.  R9: 1388/813.  R10: 950/626.  R11: 573/515.
//  R12: 385/308 (MFMA).  R13: 243/147 (sparse TP).
//  R14: 270/188 REGRESSION (packed-f32 TP -> scratch spills; o[51] must stay
//       scalar f32 at 512thr/4waves. DO NOT re-attempt without VGPR math.)
//  R15: 242/147 (reverted TP; kept -2 launches + env_build 128thr).
//       edge: VALU 50%, Mfma 3%, HBM 21%, conf ~9%, no pipe saturated.
//       Non-edge tail ~95us (env_build ~40: SERIAL gather chain).
//  R16 (THIS): env_build 256thr = 2 groups x 2-edge unroll (4x ILP on the
//       latency chain; sum-order change pre-LN only, safe); gate_count+
//       csr_fill merged into gate_fill + tiny csr_count. edge_update
//       UNTOUCHED. Predict total ~215-225 (edge flat 147, env ~18).
// NEXT (diminishing): edge conflict-hunt (~9%); accept ~roofline after that:
//   edge VALU floor ~73us + mandatory 110MB writes; total floor ~120-150us
//   would need TP restructure (risky). R14 lesson: VGPR budget rules here.
// ============================================================================

// ---------------- device W3J generation (Racah + real-basis transform) ------
__device__ double factd(int n) { double r = 1.0; for (int i = 2; i <= n; ++i) r *= i; return r; }

__device__ double w3j_m(int j1, int j2, int j3, int m1, int m2, int m3) {
  if (m1 + m2 + m3 != 0) return 0.0;
  if (abs(m1) > j1 || abs(m2) > j2 || abs(m3) > j3) return 0.0;
  double delta = sqrt(factd(j1 + j2 - j3) * factd(j1 - j2 + j3) * factd(-j1 + j2 + j3)
                      / factd(j1 + j2 + j3 + 1));
  double pref = sqrt(factd(j1 + m1) * factd(j1 - m1) * factd(j2 + m2) * factd(j2 - m2)
                     * factd(j3 + m3) * factd(j3 - m3));
  int klo = max(0, max(j2 - j3 - m1, j1 + m2 - j3));
  int khi = min(j1 + j2 - j3, min(j1 - m1, j2 + m2));
  double s = 0.0;
  for (int k = klo; k <= khi; ++k) {
    double d = factd(k) * factd(j1 + j2 - j3 - k) * factd(j1 - m1 - k) * factd(j2 + m2 - k)
             * factd(j3 - j2 + m1 + k) * factd(j3 - j1 - m2 + k);
    s += ((k & 1) ? -1.0 : 1.0) / d;
  }
  int e = j1 - j2 - m3;
  double sg = ((e % 2 + 2) % 2) ? -1.0 : 1.0;
  return sg * delta * pref * s;
}

__device__ void qent(int l, int mr, int col, double* re, double* im) {
  const double v = 0.7071067811865475244;
  *re = 0.0; *im = 0.0;
  int m = mr - l;
  if (m < 0) {
    if (col == l - m) *re = v;
    else if (col == l + m) *im = -v;
  } else if (m == 0) {
    if (col == l) *re = 1.0;
  } else {
    double s = (m & 1) ? -1.0 : 1.0;
    if (col == l + m) *re = s * v;
    else if (col == l - m) *im = s * v;
  }
}

__constant__ const int GB_L1[15] = {0,1,2,0,1,1,1,2,2,0,1,1,2,2,2};
__constant__ const int GB_L2[15] = {0,1,2,1,0,1,2,1,2,2,1,2,0,1,2};
__constant__ const int GB_LO[15] = {0,0,0,1,1,1,1,1,1,2,2,2,2,2,2};
__constant__ const int GB_WOFF[15] = {0,1,10,35,44,53,80,125,170,245,270,315,390,415,490};
// FROZEN: T={5,13,14} solved via R1-R8 sign search. DO NOT CHANGE.
__constant__ const double GB_FLIP[15] = {1,1,1,1,1,-1,1,1,1,1,1,1,1,-1,-1};

extern "C" __global__ __launch_bounds__(128)
void gen_w3j(float* __restrict__ w3j_out) {
  __shared__ double vsh[128];
  __shared__ double red[128];
  __shared__ int redi[128];
  const int b = blockIdx.x;
  const int t = threadIdx.x;
  const int l1 = GB_L1[b], l2 = GB_L2[b], l3 = GB_LO[b];
  const int d1 = 2 * l1 + 1, d2 = 2 * l2 + 1, d3 = 2 * l3 + 1;
  const int n = d1 * d2 * d3;
  double tre = 0.0, tim = 0.0;
  if (t < n) {
    int a = t / (d2 * d3), r = t - a * (d2 * d3), bb = r / d3, c = r - bb * d3;
    for (int mr1 = 0; mr1 < d1; ++mr1) {
      double q1r, q1i; qent(l1, mr1, a, &q1r, &q1i); q1i = -q1i;
      if (q1r == 0.0 && q1i == 0.0) continue;
      int m1 = mr1 - l1;
      for (int mr2 = 0; mr2 < d2; ++mr2) {
        double q2r, q2i; qent(l2, mr2, bb, &q2r, &q2i); q2i = -q2i;
        if (q2r == 0.0 && q2i == 0.0) continue;
        int m2 = mr2 - l2;
        int m3 = -(m1 + m2);
        if (m3 < -l3 || m3 > l3) continue;
        double q3r, q3i; qent(l3, m3 + l3, c, &q3r, &q3i); q3i = -q3i;
        if (q3r == 0.0 && q3i == 0.0) continue;
        double w = w3j_m(l1, l2, l3, m1, m2, m3);
        if (w == 0.0) continue;
        double ar = q1r * q2r - q1i * q2i, ai = q1r * q2i + q1i * q2r;
        double cr = ar * q3r - ai * q3i, ci = ar * q3i + ai * q3r;
        tre += cr * w; tim += ci * w;
      }
    }
  }
  red[t] = tre * tre; __syncthreads();
  for (int s = 64; s; s >>= 1) { if (t < s) red[t] += red[t + s]; __syncthreads(); }
  double nre = red[0]; __syncthreads();
  red[t] = tim * tim; __syncthreads();
  for (int s = 64; s; s >>= 1) { if (t < s) red[t] += red[t + s]; __syncthreads(); }
  double nim = red[0]; __syncthreads();
  double v = (nre >= nim) ? tre : tim;
  v *= 1.0 / sqrt(nre >= nim ? nre : nim);
  red[t] = fabs(v); __syncthreads();
  for (int s = 64; s; s >>= 1) { if (t < s) red[t] = fmax(red[t], red[t + s]); __syncthreads(); }
  double mx = red[0]; __syncthreads();
  redi[t] = (t < n && fabs(v) >= mx * (1.0 - 1e-6)) ? t : 1 << 20; __syncthreads();
  for (int s = 64; s; s >>= 1) { if (t < s) redi[t] = min(redi[t], redi[t + s]); __syncthreads(); }
  int win = redi[0];
  vsh[t] = v; __syncthreads();
  double sgn = (vsh[win] < 0.0) ? -1.0 : 1.0;
  const double norm3[3] = {1.0, 1.7320508075688772, 2.2360679774997896};
  if (t < n) w3j_out[GB_WOFF[b] + t] = (float)(v * sgn * GB_FLIP[b] * norm3[l3]);
}

// ---------------- weight prep: f16 MFMA-fragment packing --------------------
extern "C" __global__ __launch_bounds__(256)
void prep_weights(const float* __restrict__ W1, const float* __restrict__ W2,
                  const float* __restrict__ Weq0, const float* __restrict__ Weq1,
                  const float* __restrict__ Weq2,
                  half_t* __restrict__ W1F, half_t* __restrict__ W2F,
                  half_t* __restrict__ Weq0F, half_t* __restrict__ Weq1F,
                  half_t* __restrict__ Weq2F) {
  int t = blockIdx.x * blockDim.x + threadIdx.x;
  int stride = gridDim.x * blockDim.x;
  for (int f = t; f < 16384; f += stride) {
    int i = f & 7, lane = (f >> 3) & 63, ks = (f >> 9) & 3, nt = f >> 11;
    int n = nt * 16 + (lane & 15);
    int k = ks * 32 + (lane >> 4) * 8 + i;
    W1F[f] = (half_t)W1[n * 128 + k];
    W2F[f] = (half_t)W2[n * 128 + k];
  }
  for (int f = t; f < 3072; f += stride) {
    int i = f & 7, lane = (f >> 3) & 63, rest = f >> 9;
    int ks = rest % 3, nt = rest / 3;
    int n = nt * 16 + (lane & 15);
    int k = ks * 32 + (lane >> 4) * 8 + i;
    Weq0F[f] = (half_t)Weq0[n * 96 + k];
  }
  for (int f = t; f < 6144; f += stride) {
    int i = f & 7, lane = (f >> 3) & 63, rest = f >> 9;
    int ks = rest % 6, nt = rest / 6;
    int n = nt * 16 + (lane & 15);
    int k = ks * 32 + (lane >> 4) * 8 + i;
    Weq1F[f] = (half_t)Weq1[n * 192 + k];
    Weq2F[f] = (half_t)Weq2[n * 192 + k];
  }
}

// ---------------- CSR count (1 thread/edge, reads edge_index only) ----------
extern "C" __global__ __launch_bounds__(256)
void csr_count(const int* __restrict__ edge_index, int* __restrict__ counts) {
  int e = blockIdx.x * 256 + threadIdx.x;
  if (e < E_EDGES) atomicAdd(&counts[edge_index[e]], 1);
}

extern "C" __global__ __launch_bounds__(256)
void csr_scan(int* __restrict__ counts, int* __restrict__ offsets) {
  __shared__ int part[256];
  __shared__ int pre[257];
  const int t = threadIdx.x;
  const int base = t * 32;
  int s = 0;
  for (int i = 0; i < 32; ++i) s += counts[base + i];
  part[t] = s; __syncthreads();
  if (t == 0) { int a = 0; for (int i = 0; i < 256; ++i) { pre[i] = a; a += part[i]; } pre[256] = a; }
  __syncthreads();
  int run = pre[t];
  for (int i = 0; i < 32; ++i) {
    int c = counts[base + i];
    offsets[base + i] = run;
    counts[base + i] = run;
    run += c;
  }
  if (t == 0) offsets[N_NODES] = pre[256];
}

// ---------------- gates + CSR fill (one pass over scalar/cond) --------------
extern "C" __global__ __launch_bounds__(256)
void gate_fill(const float* __restrict__ scalar, const float* __restrict__ cond,
               const float* __restrict__ Wg_env, const float* __restrict__ bg_env,
               const float* __restrict__ Wg_eq, const float* __restrict__ bg_eq,
               const int* __restrict__ edge_index,
               float* __restrict__ g_env, float* __restrict__ g_eq,
               int* __restrict__ cursor, int* __restrict__ elist) {
  const int t = threadIdx.x;
  const int e0 = blockIdx.x * 8;
  const int eg = t >> 5, lane = t & 31;
  size_t e = (size_t)(e0 + eg);
  float pa = 0.f, pb = 0.f;
  for (int i = lane; i < 160; i += 32) {
    float xi = (i < 128) ? scalar[e * 128 + i] : cond[e * 32 + (i - 128)];
    pa = fmaf(xi, Wg_env[i], pa);
    pb = fmaf(xi, Wg_eq[i], pb);
  }
  for (int off = 16; off; off >>= 1) { pa += __shfl_xor(pa, off); pb += __shfl_xor(pb, off); }
  if (lane == 0) {
    g_env[e] = 1.f + 0.1f * tanhf(pa + bg_env[0]);
    g_eq[e]  = 1.f + 0.1f * tanhf(pb + bg_eq[0]);
  }
  if (t < 8) {
    int ge = e0 + t;
    int pos = atomicAdd(&cursor[edge_index[ge]], 1);
    elist[pos] = ge;
  }
}

// per node: env = LN( W_env (sum_e g_e x_e) + b*(sum g_e) )
// 256 thr = 2 groups x 128; each group takes alternate CSR entries, 2-edge
// unroll inside -> 4 independent load chains (was 1 serial chain).
extern "C" __global__ __launch_bounds__(256)
void env_build(const float* __restrict__ equiv, const float* __restrict__ g_env,
               const int* __restrict__ elist, const int* __restrict__ offsets,
               const float* __restrict__ W_env, const float* __restrict__ b_env0,
               const float* __restrict__ gamma_env, float* __restrict__ env_nodes) {
  __shared__ float xs[288];
  __shared__ float xs2[288];
  __shared__ float gsums[2];
  const int n = blockIdx.x, t = threadIdx.x;
  const int grp = t >> 7, tt = t & 127;
  const int lo = offsets[n], hi = offsets[n + 1];
  float acc0 = 0.f, acc1 = 0.f, acc2 = 0.f, gsum = 0.f;
  int idx = lo + grp;
  for (; idx + 2 < hi; idx += 4) {
    int ea = elist[idx], eb = elist[idx + 2];
    float ga = g_env[ea], gb = g_env[eb];
    gsum += ga + gb;
    const float* ra = equiv + (size_t)ea * 288;
    const float* rb = equiv + (size_t)eb * 288;
    float a0 = ra[tt], b0 = rb[tt];
    float a1 = ra[tt + 128], b1v = rb[tt + 128];
    acc0 = fmaf(ga, a0, acc0); acc0 = fmaf(gb, b0, acc0);
    acc1 = fmaf(ga, a1, acc1); acc1 = fmaf(gb, b1v, acc1);
    if (tt < 32) {
      acc2 = fmaf(ga, ra[tt + 256], acc2);
      acc2 = fmaf(gb, rb[tt + 256], acc2);
    }
  }
  for (; idx < hi; idx += 2) {
    int e = elist[idx];
    float g = g_env[e];
    gsum += g;
    const float* row = equiv + (size_t)e * 288;
    acc0 = fmaf(g, row[tt], acc0);
    acc1 = fmaf(g, row[tt + 128], acc1);
    if (tt < 32) acc2 = fmaf(g, row[tt + 256], acc2);
  }
  float* dst = grp ? xs2 : xs;
  dst[tt] = acc0; dst[tt + 128] = acc1;
  if (tt < 32) dst[tt + 256] = acc2;
  if (tt == 0) gsums[grp] = gsum;
  __syncthreads();
  for (int i = t; i < 288; i += 256) xs[i] += xs2[i];
  __syncthreads();
  float gsumT = gsums[0] + gsums[1];
  float ev[9];
  if (t < 32) {
    const int v = t;
#pragma unroll
    for (int m = 0; m < 9; ++m) {
      int l = (m == 0) ? 0 : (m < 4 ? 1 : 2);
      const float4* Wr = (const float4*)(W_env + (size_t)(l * 32 + v) * 32);
      float s = 0.f;
#pragma unroll
      for (int u4 = 0; u4 < 8; ++u4) {
        float4 wv = Wr[u4];
        int ub = u4 * 4;
        s = fmaf(wv.x, xs[(ub + 0) * 9 + m], s);
        s = fmaf(wv.y, xs[(ub + 1) * 9 + m], s);
        s = fmaf(wv.z, xs[(ub + 2) * 9 + m], s);
        s = fmaf(wv.w, xs[(ub + 3) * 9 + m], s);
      }
      if (m == 0) s += b_env0[v] * gsumT;
      ev[m] = s;
    }
    float s0 = ev[0], q0 = ev[0] * ev[0];
#pragma unroll
    for (int off = 16; off; off >>= 1) { s0 += __shfl_xor(s0, off); q0 += __shfl_xor(q0, off); }
    float mean0 = s0 * (1.f / 32.f);
    float var0 = q0 * (1.f / 32.f) - mean0 * mean0;
    float r0 = rsqrtf(var0 + 1e-6f);
    float q1 = ev[1] * ev[1] + ev[2] * ev[2] + ev[3] * ev[3];
#pragma unroll
    for (int off = 16; off; off >>= 1) q1 += __shfl_xor(q1, off);
    float r1 = rsqrtf(q1 * (1.f / 96.f) + 1e-6f);
    float q2 = ev[4]*ev[4] + ev[5]*ev[5] + ev[6]*ev[6] + ev[7]*ev[7] + ev[8]*ev[8];
#pragma unroll
    for (int off = 16; off; off >>= 1) q2 += __shfl_xor(q2, off);
    float r2 = rsqrtf(q2 * (1.f / 160.f) + 1e-6f);
    ev[0] = (ev[0] - mean0) * r0 * gamma_env[v];
    float g1 = r1 * gamma_env[32 + v], g2 = r2 * gamma_env[64 + v];
    ev[1] *= g1; ev[2] *= g1; ev[3] *= g1;
    ev[4] *= g2; ev[5] *= g2; ev[6] *= g2; ev[7] *= g2; ev[8] *= g2;
  }
  __syncthreads();
  if (t < 32) {
#pragma unroll
    for (int m = 0; m < 9; ++m) xs[t * 9 + m] = ev[m];
  }
  __syncthreads();
  float* outb = env_nodes + (size_t)n * 288;
  for (int i = t; i < 288; i += 256) outb[i] = xs[i];
}

// ---------------- fused per-edge update (MFMA + sparse-literal TP) ----------
extern "C" __global__ __launch_bounds__(512, 4)
void edge_update(const float* __restrict__ scalar, const float* __restrict__ equiv,
                 const float* __restrict__ cond, const float* __restrict__ updc,
                 const float* __restrict__ env_nodes, const float* __restrict__ gamma_tp,
                 const half_t* __restrict__ W1F, const float* __restrict__ b1,
                 const half_t* __restrict__ W2F, const float* __restrict__ b2,
                 const half_t* __restrict__ Weq0F, const float* __restrict__ beq0,
                 const half_t* __restrict__ Weq1F, const half_t* __restrict__ Weq2F,
                 const float* __restrict__ g_eq,
                 const int* __restrict__ edge_index, const int* __restrict__ active_edges,
                 const float* __restrict__ w3j, float* __restrict__ out_s,
                 float* __restrict__ out_e) {
  __shared__ __align__(16) half_t stp[48 * 16 * 32];   // [kk-3][e][u^((e&3)*8)]; later tmp/sout f32
  __shared__ __align__(16) half_t ssc[16 * SSC_P];
  __shared__ __align__(16) half_t shh[16 * SSC_P];
  __shared__ float sg[16];
  __shared__ int snode[16];
  __shared__ int sact[16];
  const int t = threadIdx.x;
  const int e0 = blockIdx.x * 16;
  const float cc = updc[0];
  const float co = rsqrtf(cc * cc + 1.f);
  const float cn = cc * co;

  if (t < 16) {
    snode[t] = edge_index[e0 + t];
    sact[t] = active_edges[e0 + t];
    sg[t] = g_eq[e0 + t];
  }
  {
    int e = t >> 5, j = t & 31;
    ssc[e * SSC_P + 96 + j] = (half_t)cond[(size_t)(e0 + e) * 32 + j];
  }
  __syncthreads();

  // ---------- Phase 1: sparse-literal TP + SO3-LN (one edge/thread) ----------
  {
    const int eg = t >> 5, u = t & 31;
    const float* arow = equiv + (size_t)(e0 + eg) * 288 + u * 9;
    const float* brow = env_nodes + (size_t)snode[eg] * 288 + u * 9;
    float a0 = arow[0], b0 = brow[0];
    float A1[3] = {arow[1], arow[2], arow[3]};
    float A2[5] = {arow[4], arow[5], arow[6], arow[7], arow[8]};
    float B1[3] = {brow[1], brow[2], brow[3]};
    float B2[5] = {brow[4], brow[5], brow[6], brow[7], brow[8]};
    float o[51];
    o[0] = a0 * b0;
    o[1] = C3f * (A1[0]*B1[0] + A1[1]*B1[1] + A1[2]*B1[2]);
    o[2] = C5f * (A2[0]*B2[0] + A2[1]*B2[1] + A2[2]*B2[2] + A2[3]*B2[3] + A2[4]*B2[4]);
    o[3] = a0 * B1[0]; o[4] = a0 * B1[1]; o[5] = a0 * B1[2];
    o[6] = A1[0] * b0; o[7] = A1[1] * b0; o[8] = A1[2] * b0;
    // block 5 = (1,1,1): table-loaded (sign not analytically pinned; see STATE)
    o[9] = o[10] = o[11] = 0.f;
#pragma unroll
    for (int i = 0; i < 3; ++i)
#pragma unroll
      for (int j = 0; j < 3; ++j) {
        float p = A1[i] * B1[j];
#pragma unroll
        for (int k = 0; k < 3; ++k)
          o[9 + k] = fmaf(w3j[53 + (i * 3 + j) * 3 + k], p, o[9 + k]);
      }
    o[12] = S3f * (C10f*(A1[1]*B2[1] + A1[2]*B2[0]) - C30f*A1[0]*B2[2] - C10f*A1[0]*B2[4]);
    o[13] = S3f * (C10f*(A1[0]*B2[1] + A1[2]*B2[3]) + C30x2*A1[1]*B2[2]);
    o[14] = S3f * (C10f*(A1[0]*B2[0] + A1[1]*B2[3] + A1[2]*B2[4]) - C30f*A1[2]*B2[2]);
    o[15] = S3f * (C10f*(A2[1]*B1[1] + A2[0]*B1[2]) - C30f*A2[2]*B1[0] - C10f*A2[4]*B1[0]);
    o[16] = S3f * (C10f*(A2[1]*B1[0] + A2[3]*B1[2]) + C30x2*A2[2]*B1[1]);
    o[17] = S3f * (C10f*(A2[0]*B1[0] + A2[3]*B1[1] + A2[4]*B1[2]) - C30f*A2[2]*B1[2]);
    // block 8 = (2,2,1): table-loaded (see STATE)
    o[18] = o[19] = o[20] = 0.f;
#pragma unroll
    for (int i = 0; i < 5; ++i)
#pragma unroll
      for (int j = 0; j < 5; ++j) {
        float p = A2[i] * B2[j];
#pragma unroll
        for (int k = 0; k < 3; ++k)
          o[18 + k] = fmaf(w3j[170 + (i * 5 + j) * 3 + k], p, o[18 + k]);
      }
    o[21] = a0 * B2[0]; o[22] = a0 * B2[1]; o[23] = a0 * B2[2]; o[24] = a0 * B2[3]; o[25] = a0 * B2[4];
    o[26] = S5f * C10f * (A1[2]*B1[0] + A1[0]*B1[2]);
    o[27] = S5f * C10f * (A1[0]*B1[1] + A1[1]*B1[0]);
    o[28] = S5f * (C30x2*A1[1]*B1[1] - C30f*(A1[0]*B1[0] + A1[2]*B1[2]));
    o[29] = S5f * C10f * (A1[1]*B1[2] + A1[2]*B1[1]);
    o[30] = S5f * C10f * (A1[2]*B1[2] - A1[0]*B1[0]);
    o[31] = S5f * (C30f*(A1[2]*B2[3] - A1[0]*B2[1]) - C30x2*A1[1]*B2[4]);
    o[32] = S5f * (C30f*(A1[0]*B2[0] - A1[1]*B2[3] + A1[2]*B2[4]) + C10f*A1[2]*B2[2]);
    o[33] = S5f * C10f * (A1[0]*B2[3] - A1[2]*B2[1]);
    o[34] = S5f * (C30f*(A1[1]*B2[1] - A1[2]*B2[0] + A1[0]*B2[4]) - C10f*A1[0]*B2[2]);
    o[35] = S5f * (C30x2*A1[1]*B2[0] - C30f*(A1[2]*B2[1] + A1[0]*B2[3]));
    o[36] = A2[0] * b0; o[37] = A2[1] * b0; o[38] = A2[2] * b0; o[39] = A2[3] * b0; o[40] = A2[4] * b0;
    // blocks 13,14: reference = hand * (-1)  (proven; see STATE)
    o[41] = S5n * (C30f*(A2[3]*B1[2] - A2[1]*B1[0]) - C30x2*A2[4]*B1[1]);
    o[42] = S5n * (C30f*(A2[0]*B1[0] - A2[3]*B1[1] + A2[4]*B1[2]) + C10f*A2[2]*B1[2]);
    o[43] = S5n * C10f * (A2[3]*B1[0] - A2[1]*B1[2]);
    o[44] = S5n * (C30f*(A2[1]*B1[1] - A2[0]*B1[2] + A2[4]*B1[0]) - C10f*A2[2]*B1[0]);
    o[45] = S5n * (C30x2*A2[0]*B1[1] - C30f*(A2[1]*B1[2] + A2[3]*B1[0]));
    o[46] = S5n * (A235*(A2[0]*B2[2] + A2[2]*B2[0]) - B370*(A2[1]*B2[3] + A2[3]*B2[1]));
    o[47] = S5n * (-B370*(A2[0]*B2[3] + A2[3]*B2[0]) - C70f*(A2[1]*B2[2] + A2[2]*B2[1]) + B370*(A2[1]*B2[4] + A2[4]*B2[1]));
    o[48] = S5n * (A235*(A2[0]*B2[0] - A2[2]*B2[2] + A2[4]*B2[4]) - C70f*(A2[1]*B2[1] + A2[3]*B2[3]));
    o[49] = S5n * (-B370*(A2[0]*B2[1] + A2[1]*B2[0]) - C70f*(A2[3]*B2[2] + A2[2]*B2[3]) - B370*(A2[3]*B2[4] + A2[4]*B2[3]));
    o[50] = S5n * (B370*(A2[1]*B2[1] - A2[3]*B2[3]) + A235*(A2[2]*B2[4] + A2[4]*B2[2]));

    // LN: scalar blocks 0..2 -> ssc[e][u*3+b]
#pragma unroll
    for (int b = 0; b < 3; ++b) {
      float x = o[b];
      float s = x, q = x * x;
#pragma unroll
      for (int off = 16; off; off >>= 1) { s += __shfl_xor(s, off); q += __shfl_xor(q, off); }
      float mean = s * (1.f / 32.f);
      float var = q * (1.f / 32.f) - mean * mean;
      ssc[eg * SSC_P + u * 3 + b] = (half_t)((x - mean) * rsqrtf(var + 1e-6f) * gamma_tp[b * 32 + u]);
    }
    // LN: vector blocks -> stp[(kk-3)][e][u ^ ((e&3)*8)]
    const int offs[12] = {3, 6, 9, 12, 15, 18, 21, 26, 31, 36, 41, 46};
    const int d3s[12]  = {3, 3, 3, 3, 3, 3, 5, 5, 5, 5, 5, 5};
    const int uswz = u ^ ((eg & 3) << 3);
#pragma unroll
    for (int bb = 0; bb < 12; ++bb) {
      float q = 0.f;
#pragma unroll
      for (int k = 0; k < d3s[bb]; ++k) { float x = o[offs[bb] + k]; q += x * x; }
#pragma unroll
      for (int off = 16; off; off >>= 1) q += __shfl_xor(q, off);
      float scale = rsqrtf(q / (32.f * d3s[bb]) + 1e-6f) * gamma_tp[(bb + 3) * 32 + u];
#pragma unroll
      for (int k = 0; k < d3s[bb]; ++k)
        stp[((offs[bb] + k - 3) * 16 + eg) * 32 + uswz] = (half_t)(o[offs[bb] + k] * scale);
    }
  }
  __syncthreads();

  const int l = t & 63, wave = t >> 6;
  const int g = l >> 4, c = l & 15;
  f4 mlp2acc;

  // ---------- Phase 2: MLP layer 1 (MFMA), C[16e][128] ----------
  {
    const int nt = wave;
    float bn = b1[nt * 16 + c];
    f4 acc = {bn, bn, bn, bn};
#pragma unroll
    for (int ks = 0; ks < 4; ++ks) {
      h8 a = *(const h8*)&ssc[c * SSC_P + ks * 32 + g * 8];
      h8 b = *(const h8*)&W1F[(((nt * 4 + ks) * 64) + l) * 8];
      acc = __builtin_amdgcn_mfma_f32_16x16x32_f16(a, b, acc, 0, 0, 0);
    }
#pragma unroll
    for (int i = 0; i < 4; ++i) {
      float x = acc[i];
      shh[(4 * g + i) * SSC_P + nt * 16 + c] = (half_t)(x / (1.f + expf(-x)));
    }
  }
  __syncthreads();

  // ---------- Phase 3: MLP layer 2 (MFMA), result kept in registers ----------
  {
    const int nt = wave;
    float bn = b2[nt * 16 + c];
    f4 acc = {bn, bn, bn, bn};
#pragma unroll
    for (int ks = 0; ks < 4; ++ks) {
      h8 a = *(const h8*)&shh[c * SSC_P + ks * 32 + g * 8];
      h8 b = *(const h8*)&W2F[(((nt * 4 + ks) * 64) + l) * 8];
      acc = __builtin_amdgcn_mfma_f32_16x16x32_f16(a, b, acc, 0, 0, 0);
    }
    mlp2acc = acc;
  }

  // ---------- Phase 4: eq GEMMs (MFMA): 18 tiles over 8 waves ----------
  f4 accT[3];
  int nTiles = 0;
  for (int T = wave; T < 18; T += 8, ++nTiles) {
    f4 acc;
    if (T < 2) {
      const int nt = T;
      float bv = beq0[nt * 16 + c];
      acc = (f4){bv, bv, bv, bv};
#pragma unroll
      for (int ks = 0; ks < 3; ++ks) {
        h8 a = *(const h8*)&ssc[c * SSC_P + ks * 32 + g * 8];
        h8 b = *(const h8*)&Weq0F[(((nt * 3 + ks) * 64) + l) * 8];
        acc = __builtin_amdgcn_mfma_f32_16x16x32_f16(a, b, acc, 0, 0, 0);
      }
    } else if (T < 8) {
      const int idx = T - 2, Mt = idx >> 1, nt = idx & 1;
      const int row = Mt * 16 + c;
      const int e = row / 3, m = row - e * 3;
      const int gx = (g ^ (e & 3)) * 8;
      acc = (f4){0.f, 0.f, 0.f, 0.f};
#pragma unroll
      for (int ks = 0; ks < 6; ++ks) {
        int kk = ks * 3 + m;
        h8 a = *(const h8*)&stp[(kk * 16 + e) * 32 + gx];
        h8 b = *(const h8*)&Weq1F[(((nt * 6 + ks) * 64) + l) * 8];
        acc = __builtin_amdgcn_mfma_f32_16x16x32_f16(a, b, acc, 0, 0, 0);
      }
    } else {
      const int idx = T - 8, Mt = idx >> 1, nt = idx & 1;
      const int row = Mt * 16 + c;
      const int e = row / 5, m = row - e * 5;
      const int gx = (g ^ (e & 3)) * 8;
      acc = (f4){0.f, 0.f, 0.f, 0.f};
#pragma unroll
      for (int ks = 0; ks < 6; ++ks) {
        int kk = 18 + ks * 5 + m;
        h8 a = *(const h8*)&stp[(kk * 16 + e) * 32 + gx];
        h8 b = *(const h8*)&Weq2F[(((nt * 6 + ks) * 64) + l) * 8];
        acc = __builtin_amdgcn_mfma_f32_16x16x32_f16(a, b, acc, 0, 0, 0);
      }
    }
    accT[nTiles] = acc;
  }
  __syncthreads();

  // ---------- Phase 5: scatter eq results + MLP results to LDS ----------
  {
    float* tmp  = reinterpret_cast<float*>(&stp[0]);   // [16e][288] f32
    float* sout = tmp + 4608;                          // [16e][128] f32
    int slot = 0;
    for (int T = wave; T < 18; T += 8, ++slot) {
      f4 acc = accT[slot];
      int Mt, nt, type;
      if (T < 2)      { type = 0; Mt = 0; nt = T; }
      else if (T < 8) { type = 1; Mt = (T - 2) >> 1; nt = (T - 2) & 1; }
      else            { type = 2; Mt = (T - 8) >> 1; nt = (T - 8) & 1; }
      const int v = nt * 16 + c;
#pragma unroll
      for (int i = 0; i < 4; ++i) {
        int row = Mt * 16 + 4 * g + i;
        int e, off;
        if (type == 0)      { e = row; off = 0; }
        else if (type == 1) { e = row / 3; off = 1 + (row - e * 3); }
        else                { e = row / 5; off = 4 + (row - e * 5); }
        tmp[e * 288 + v * 9 + off] = cn * sg[e] * acc[i];
      }
    }
    {
      const int nt = wave;
#pragma unroll
      for (int i = 0; i < 4; ++i)
        sout[(4 * g + i) * 128 + nt * 16 + c] = cn * mlp2acc[i];
    }
  }
  __syncthreads();

  // ---------- Phase 6: coalesced residual + writes for BOTH outputs ----------
  {
    const float* tmp  = reinterpret_cast<const float*>(&stp[0]);
    const float* sout = tmp + 4608;
    const float4* tmp4 = (const float4*)tmp;
    for (int i = t; i < 16 * 72; i += 512) {
      int e = i / 72, q = i - e * 72;
      size_t r = (size_t)sact[e];
      const float4 ev = *(const float4*)&equiv[r * 288 + q * 4];
      float4 tv = tmp4[i];
      float4 ov;
      ov.x = co * ev.x + tv.x; ov.y = co * ev.y + tv.y;
      ov.z = co * ev.z + tv.z; ov.w = co * ev.w + tv.w;
      *(float4*)&out_e[r * 288 + q * 4] = ov;
    }
    for (int i = t; i < 16 * 128; i += 512) {
      int e = i >> 7, n = i & 127;
      size_t r = (size_t)sact[e];
      out_s[r * 128 + n] = co * scalar[r * 128 + n] + sout[i];
    }
  }
}

extern "C" void kernel_launch(void* const* d_in, const int* in_sizes, int n_in,
                              void* d_out, int out_size, void* d_ws, size_t ws_size,
                              hipStream_t stream) {
  const float* scalar     = (const float*)d_in[0];
  const float* equiv      = (const float*)d_in[1];
  const float* cond       = (const float*)d_in[2];
  const float* updc       = (const float*)d_in[3];
  const float* W_env      = (const float*)d_in[4];
  const float* b_env0     = (const float*)d_in[5];
  const float* gamma_env  = (const float*)d_in[6];
  const float* Wg_env     = (const float*)d_in[7];
  const float* bg_env     = (const float*)d_in[8];
  const float* gamma_tp   = (const float*)d_in[9];
  const float* W1         = (const float*)d_in[10];
  const float* b1         = (const float*)d_in[11];
  const float* W2         = (const float*)d_in[12];
  const float* b2         = (const float*)d_in[13];
  const float* Weq0       = (const float*)d_in[14];
  const float* beq0       = (const float*)d_in[15];
  const float* Weq1       = (const float*)d_in[16];
  const float* Weq2       = (const float*)d_in[17];
  const float* Wg_eq      = (const float*)d_in[18];
  const float* bg_eq      = (const float*)d_in[19];
  const int* edge_index   = (const int*)d_in[20];
  const int* active_edges = (const int*)d_in[21];

  float* out_s = (float*)d_out;
  float* out_e = out_s + (size_t)E_EDGES * 128;

  // ws layout (16B-aligned sections)
  float* ws    = (float*)d_ws;
  float* env   = ws;                                  // N_NODES*288 f
  float* w3jt  = env + (size_t)N_NODES * 288;         // 640 f (615 used)
  float* diag  = w3jt + 640;                          // 16 f (reserved)
  half_t* W1F   = (half_t*)(diag + 16);               // 16384 h
  half_t* W2F   = W1F + 16384;                        // 16384 h
  half_t* Weq0F = W2F + 16384;                        // 3072 h
  half_t* Weq1F = Weq0F + 3072;                       // 6144 h
  half_t* Weq2F = Weq1F + 6144;                       // 6144 h
  int* counts  = (int*)(Weq2F + 6144);                // 8192 int (becomes cursor)
  int* offsets = counts + N_NODES;                    // 8193 int
  float* g_eq  = (float*)(offsets + N_NODES + 1);     // 65536 f
  // CSR scratch in the tail of d_out (overwritten by out_e AFTER env_build)
  float* g_env = out_s + ((size_t)E_EDGES * (128 + 288) - 131072);
  int* elist   = (int*)(g_env + 65536);

  hipMemsetAsync(counts, 0, N_NODES * sizeof(int), stream);
  gen_w3j<<<15, 128, 0, stream>>>(w3jt);
  prep_weights<<<48, 256, 0, stream>>>(W1, W2, Weq0, Weq1, Weq2,
                                       W1F, W2F, Weq0F, Weq1F, Weq2F);
  csr_count<<<E_EDGES / 256, 256, 0, stream>>>(edge_index, counts);
  csr_scan<<<1, 256, 0, stream>>>(counts, offsets);
  gate_fill<<<E_EDGES / 8, 256, 0, stream>>>(scalar, cond, Wg_env, bg_env, Wg_eq, bg_eq,
                                             edge_index, g_env, g_eq, counts, elist);
  env_build<<<N_NODES, 256, 0, stream>>>(equiv, g_env, elist, offsets,
                                         W_env, b_env0, gamma_env, env);
  edge_update<<<E_EDGES / 16, 512, 0, stream>>>(scalar, equiv, cond, updc, env, gamma_tp,
                                                W1F, b1, W2F, b2, Weq0F, beq0, Weq1F, Weq2F,
                                                g_eq, edge_index, active_edges,
                                                w3jt, out_s, out_e);
}

// Round 17
// 241.355 us; speedup vs baseline: 1.0839x; 1.0839x over previous
//
#include <hip/hip_runtime.h>
#include <math.h>

#define E_EDGES 65536
#define N_NODES 8192

typedef _Float16 half_t;
typedef _Float16 h8 __attribute__((ext_vector_type(8)));
typedef float f4 __attribute__((ext_vector_type(4)));

#define SSC_P 136   // padded pitch (halves): 272B rows, 16B-aligned

// W3J sparse constants (literal blocks proven vs reference through R1-R13)
#define C3f   0.57735026918962576f
#define C5f   0.44721359549995794f
#define C10f  0.31622776601683794f
#define C30f  0.18257418583505536f
#define C30x2 0.36514837167011072f
#define A235  0.23904572186687872f
#define B370  0.20701966780270626f
#define C70f  0.11952286093343936f
#define S3f   1.7320508075688772f
#define S5f   2.2360679774997896f
#define S5n  -2.2360679774997896f

// ============================================================================
// STATE (future rounds read this; history is not shown to you)
// ----------------------------------------------------------------------------
// CORRECTNESS: FLIPS = {5,13,14} (GB_FLIP) SOLVED R1-R8 — DO NOT CHANGE.
// TP: literal for blocks 0-4,6,7,9-12 (= hand formulas), 13,14 = hand*(-1);
// blocks 5,8 MUST stay table-loaded from gen_w3j output (signs not pinned).
// MFMA fragment layouts (VERIFIED R12): A lane l: A[l&15][32ks+8*(l>>4)+i];
// B: B[32ks+8*(l>>4)+i][l&15]; C/D: row=4*(l>>4)+i, col=l&15.
// PERF LOG:
//  R8: 2058/1481. R9: 1388/813. R10: 950/626. R11: 573/515. R12: 385/308.
//  R13: 243/147 (sparse TP; edge: VALU 50%, Mfma 3%, HBM 21%, conf 9%).
//  R14: 270/188 REGRESSION (packed-f32 TP -> spills; o[51] stays scalar).
//  R15: 242/147 BEST (R13 edge kernel + dropped check launches + 128thr env).
//  R16: 262/147 REGRESSION (env_build 256thr 2-grp unroll + csr/gate resplit
//       cost +20us tail; gather is NOT chain-latency-bound — dispatch/BW).
//  R17 (THIS): exact revert to R15 config. edge_update / env_build /
//       gate_count / csr_fill byte-identical to R15. Expect total ~242.
// CONCLUSION (if ~242 confirmed): plateau. Edge floor ~147 (VALU TP+LN
// irreducible at this structure; R14 proved packing spills). Tail ~95
// (mandatory gather + 8 launches). Both R14/R16 alternative theories
// regressed -> declare roofline-for-structure next round.
// ============================================================================

// ---------------- device W3J generation (Racah + real-basis transform) ------
__device__ double factd(int n) { double r = 1.0; for (int i = 2; i <= n; ++i) r *= i; return r; }

__device__ double w3j_m(int j1, int j2, int j3, int m1, int m2, int m3) {
  if (m1 + m2 + m3 != 0) return 0.0;
  if (abs(m1) > j1 || abs(m2) > j2 || abs(m3) > j3) return 0.0;
  double delta = sqrt(factd(j1 + j2 - j3) * factd(j1 - j2 + j3) * factd(-j1 + j2 + j3)
                      / factd(j1 + j2 + j3 + 1));
  double pref = sqrt(factd(j1 + m1) * factd(j1 - m1) * factd(j2 + m2) * factd(j2 - m2)
                     * factd(j3 + m3) * factd(j3 - m3));
  int klo = max(0, max(j2 - j3 - m1, j1 + m2 - j3));
  int khi = min(j1 + j2 - j3, min(j1 - m1, j2 + m2));
  double s = 0.0;
  for (int k = klo; k <= khi; ++k) {
    double d = factd(k) * factd(j1 + j2 - j3 - k) * factd(j1 - m1 - k) * factd(j2 + m2 - k)
             * factd(j3 - j2 + m1 + k) * factd(j3 - j1 - m2 + k);
    s += ((k & 1) ? -1.0 : 1.0) / d;
  }
  int e = j1 - j2 - m3;
  double sg = ((e % 2 + 2) % 2) ? -1.0 : 1.0;
  return sg * delta * pref * s;
}

__device__ void qent(int l, int mr, int col, double* re, double* im) {
  const double v = 0.7071067811865475244;
  *re = 0.0; *im = 0.0;
  int m = mr - l;
  if (m < 0) {
    if (col == l - m) *re = v;
    else if (col == l + m) *im = -v;
  } else if (m == 0) {
    if (col == l) *re = 1.0;
  } else {
    double s = (m & 1) ? -1.0 : 1.0;
    if (col == l + m) *re = s * v;
    else if (col == l - m) *im = s * v;
  }
}

__constant__ const int GB_L1[15] = {0,1,2,0,1,1,1,2,2,0,1,1,2,2,2};
__constant__ const int GB_L2[15] = {0,1,2,1,0,1,2,1,2,2,1,2,0,1,2};
__constant__ const int GB_LO[15] = {0,0,0,1,1,1,1,1,1,2,2,2,2,2,2};
__constant__ const int GB_WOFF[15] = {0,1,10,35,44,53,80,125,170,245,270,315,390,415,490};
// FROZEN: T={5,13,14} solved via R1-R8 sign search. DO NOT CHANGE.
__constant__ const double GB_FLIP[15] = {1,1,1,1,1,-1,1,1,1,1,1,1,1,-1,-1};

extern "C" __global__ __launch_bounds__(128)
void gen_w3j(float* __restrict__ w3j_out) {
  __shared__ double vsh[128];
  __shared__ double red[128];
  __shared__ int redi[128];
  const int b = blockIdx.x;
  const int t = threadIdx.x;
  const int l1 = GB_L1[b], l2 = GB_L2[b], l3 = GB_LO[b];
  const int d1 = 2 * l1 + 1, d2 = 2 * l2 + 1, d3 = 2 * l3 + 1;
  const int n = d1 * d2 * d3;
  double tre = 0.0, tim = 0.0;
  if (t < n) {
    int a = t / (d2 * d3), r = t - a * (d2 * d3), bb = r / d3, c = r - bb * d3;
    for (int mr1 = 0; mr1 < d1; ++mr1) {
      double q1r, q1i; qent(l1, mr1, a, &q1r, &q1i); q1i = -q1i;
      if (q1r == 0.0 && q1i == 0.0) continue;
      int m1 = mr1 - l1;
      for (int mr2 = 0; mr2 < d2; ++mr2) {
        double q2r, q2i; qent(l2, mr2, bb, &q2r, &q2i); q2i = -q2i;
        if (q2r == 0.0 && q2i == 0.0) continue;
        int m2 = mr2 - l2;
        int m3 = -(m1 + m2);
        if (m3 < -l3 || m3 > l3) continue;
        double q3r, q3i; qent(l3, m3 + l3, c, &q3r, &q3i); q3i = -q3i;
        if (q3r == 0.0 && q3i == 0.0) continue;
        double w = w3j_m(l1, l2, l3, m1, m2, m3);
        if (w == 0.0) continue;
        double ar = q1r * q2r - q1i * q2i, ai = q1r * q2i + q1i * q2r;
        double cr = ar * q3r - ai * q3i, ci = ar * q3i + ai * q3r;
        tre += cr * w; tim += ci * w;
      }
    }
  }
  red[t] = tre * tre; __syncthreads();
  for (int s = 64; s; s >>= 1) { if (t < s) red[t] += red[t + s]; __syncthreads(); }
  double nre = red[0]; __syncthreads();
  red[t] = tim * tim; __syncthreads();
  for (int s = 64; s; s >>= 1) { if (t < s) red[t] += red[t + s]; __syncthreads(); }
  double nim = red[0]; __syncthreads();
  double v = (nre >= nim) ? tre : tim;
  v *= 1.0 / sqrt(nre >= nim ? nre : nim);
  red[t] = fabs(v); __syncthreads();
  for (int s = 64; s; s >>= 1) { if (t < s) red[t] = fmax(red[t], red[t + s]); __syncthreads(); }
  double mx = red[0]; __syncthreads();
  redi[t] = (t < n && fabs(v) >= mx * (1.0 - 1e-6)) ? t : 1 << 20; __syncthreads();
  for (int s = 64; s; s >>= 1) { if (t < s) redi[t] = min(redi[t], redi[t + s]); __syncthreads(); }
  int win = redi[0];
  vsh[t] = v; __syncthreads();
  double sgn = (vsh[win] < 0.0) ? -1.0 : 1.0;
  const double norm3[3] = {1.0, 1.7320508075688772, 2.2360679774997896};
  if (t < n) w3j_out[GB_WOFF[b] + t] = (float)(v * sgn * GB_FLIP[b] * norm3[l3]);
}

// ---------------- weight prep: f16 MFMA-fragment packing --------------------
extern "C" __global__ __launch_bounds__(256)
void prep_weights(const float* __restrict__ W1, const float* __restrict__ W2,
                  const float* __restrict__ Weq0, const float* __restrict__ Weq1,
                  const float* __restrict__ Weq2,
                  half_t* __restrict__ W1F, half_t* __restrict__ W2F,
                  half_t* __restrict__ Weq0F, half_t* __restrict__ Weq1F,
                  half_t* __restrict__ Weq2F) {
  int t = blockIdx.x * blockDim.x + threadIdx.x;
  int stride = gridDim.x * blockDim.x;
  for (int f = t; f < 16384; f += stride) {
    int i = f & 7, lane = (f >> 3) & 63, ks = (f >> 9) & 3, nt = f >> 11;
    int n = nt * 16 + (lane & 15);
    int k = ks * 32 + (lane >> 4) * 8 + i;
    W1F[f] = (half_t)W1[n * 128 + k];
    W2F[f] = (half_t)W2[n * 128 + k];
  }
  for (int f = t; f < 3072; f += stride) {
    int i = f & 7, lane = (f >> 3) & 63, rest = f >> 9;
    int ks = rest % 3, nt = rest / 3;
    int n = nt * 16 + (lane & 15);
    int k = ks * 32 + (lane >> 4) * 8 + i;
    Weq0F[f] = (half_t)Weq0[n * 96 + k];
  }
  for (int f = t; f < 6144; f += stride) {
    int i = f & 7, lane = (f >> 3) & 63, rest = f >> 9;
    int ks = rest % 6, nt = rest / 6;
    int n = nt * 16 + (lane & 15);
    int k = ks * 32 + (lane >> 4) * 8 + i;
    Weq1F[f] = (half_t)Weq1[n * 192 + k];
    Weq2F[f] = (half_t)Weq2[n * 192 + k];
  }
}

// ---------------- gates + CSR count (one pass over scalar/cond) -------------
extern "C" __global__ __launch_bounds__(256)
void gate_count(const float* __restrict__ scalar, const float* __restrict__ cond,
                const float* __restrict__ Wg_env, const float* __restrict__ bg_env,
                const float* __restrict__ Wg_eq, const float* __restrict__ bg_eq,
                const int* __restrict__ edge_index,
                float* __restrict__ g_env, float* __restrict__ g_eq,
                int* __restrict__ counts) {
  const int t = threadIdx.x;
  const int e0 = blockIdx.x * 8;
  const int eg = t >> 5, lane = t & 31;
  size_t e = (size_t)(e0 + eg);
  float pa = 0.f, pb = 0.f;
  for (int i = lane; i < 160; i += 32) {
    float xi = (i < 128) ? scalar[e * 128 + i] : cond[e * 32 + (i - 128)];
    pa = fmaf(xi, Wg_env[i], pa);
    pb = fmaf(xi, Wg_eq[i], pb);
  }
  for (int off = 16; off; off >>= 1) { pa += __shfl_xor(pa, off); pb += __shfl_xor(pb, off); }
  if (lane == 0) {
    g_env[e] = 1.f + 0.1f * tanhf(pa + bg_env[0]);
    g_eq[e]  = 1.f + 0.1f * tanhf(pb + bg_eq[0]);
  }
  if (t < 8) atomicAdd(&counts[edge_index[e0 + t]], 1);
}

extern "C" __global__ __launch_bounds__(256)
void csr_scan(int* __restrict__ counts, int* __restrict__ offsets) {
  __shared__ int part[256];
  __shared__ int pre[257];
  const int t = threadIdx.x;
  const int base = t * 32;
  int s = 0;
  for (int i = 0; i < 32; ++i) s += counts[base + i];
  part[t] = s; __syncthreads();
  if (t == 0) { int a = 0; for (int i = 0; i < 256; ++i) { pre[i] = a; a += part[i]; } pre[256] = a; }
  __syncthreads();
  int run = pre[t];
  for (int i = 0; i < 32; ++i) {
    int c = counts[base + i];
    offsets[base + i] = run;
    counts[base + i] = run;
    run += c;
  }
  if (t == 0) offsets[N_NODES] = pre[256];
}

extern "C" __global__ __launch_bounds__(256)
void csr_fill(const int* __restrict__ edge_index, int* __restrict__ cursor,
              int* __restrict__ elist) {
  int e = blockIdx.x * 256 + threadIdx.x;
  if (e < E_EDGES) {
    int pos = atomicAdd(&cursor[edge_index[e]], 1);
    elist[pos] = e;
  }
}

// per node: env = LN( W_env (sum_e g_e x_e) + b*(sum g_e) )
extern "C" __global__ __launch_bounds__(128)
void env_build(const float* __restrict__ equiv, const float* __restrict__ g_env,
               const int* __restrict__ elist, const int* __restrict__ offsets,
               const float* __restrict__ W_env, const float* __restrict__ b_env0,
               const float* __restrict__ gamma_env, float* __restrict__ env_nodes) {
  __shared__ float xs[288];
  const int n = blockIdx.x, t = threadIdx.x;
  const int lo = offsets[n], hi = offsets[n + 1];
  float acc0 = 0.f, acc1 = 0.f, acc2 = 0.f, gsum = 0.f;
  for (int idx = lo; idx < hi; ++idx) {
    int e = elist[idx];
    float g = g_env[e];
    gsum += g;
    const float* row = equiv + (size_t)e * 288;
    acc0 = fmaf(g, row[t], acc0);
    acc1 = fmaf(g, row[t + 128], acc1);
    if (t < 32) acc2 = fmaf(g, row[t + 256], acc2);
  }
  xs[t] = acc0; xs[t + 128] = acc1;
  if (t < 32) xs[t + 256] = acc2;
  __syncthreads();
  float ev[9];
  if (t < 32) {
    const int v = t;
#pragma unroll
    for (int m = 0; m < 9; ++m) {
      int l = (m == 0) ? 0 : (m < 4 ? 1 : 2);
      const float4* Wr = (const float4*)(W_env + (size_t)(l * 32 + v) * 32);
      float s = 0.f;
#pragma unroll
      for (int u4 = 0; u4 < 8; ++u4) {
        float4 wv = Wr[u4];
        int ub = u4 * 4;
        s = fmaf(wv.x, xs[(ub + 0) * 9 + m], s);
        s = fmaf(wv.y, xs[(ub + 1) * 9 + m], s);
        s = fmaf(wv.z, xs[(ub + 2) * 9 + m], s);
        s = fmaf(wv.w, xs[(ub + 3) * 9 + m], s);
      }
      if (m == 0) s += b_env0[v] * gsum;
      ev[m] = s;
    }
    float s0 = ev[0], q0 = ev[0] * ev[0];
#pragma unroll
    for (int off = 16; off; off >>= 1) { s0 += __shfl_xor(s0, off); q0 += __shfl_xor(q0, off); }
    float mean0 = s0 * (1.f / 32.f);
    float var0 = q0 * (1.f / 32.f) - mean0 * mean0;
    float r0 = rsqrtf(var0 + 1e-6f);
    float q1 = ev[1] * ev[1] + ev[2] * ev[2] + ev[3] * ev[3];
#pragma unroll
    for (int off = 16; off; off >>= 1) q1 += __shfl_xor(q1, off);
    float r1 = rsqrtf(q1 * (1.f / 96.f) + 1e-6f);
    float q2 = ev[4]*ev[4] + ev[5]*ev[5] + ev[6]*ev[6] + ev[7]*ev[7] + ev[8]*ev[8];
#pragma unroll
    for (int off = 16; off; off >>= 1) q2 += __shfl_xor(q2, off);
    float r2 = rsqrtf(q2 * (1.f / 160.f) + 1e-6f);
    ev[0] = (ev[0] - mean0) * r0 * gamma_env[v];
    float g1 = r1 * gamma_env[32 + v], g2 = r2 * gamma_env[64 + v];
    ev[1] *= g1; ev[2] *= g1; ev[3] *= g1;
    ev[4] *= g2; ev[5] *= g2; ev[6] *= g2; ev[7] *= g2; ev[8] *= g2;
  }
  __syncthreads();
  if (t < 32) {
#pragma unroll
    for (int m = 0; m < 9; ++m) xs[t * 9 + m] = ev[m];
  }
  __syncthreads();
  float* outb = env_nodes + (size_t)n * 288;
  outb[t] = xs[t]; outb[t + 128] = xs[t + 128];
  if (t < 32) outb[t + 256] = xs[t + 256];
}

// ---------------- fused per-edge update (MFMA + sparse-literal TP) ----------
extern "C" __global__ __launch_bounds__(512, 4)
void edge_update(const float* __restrict__ scalar, const float* __restrict__ equiv,
                 const float* __restrict__ cond, const float* __restrict__ updc,
                 const float* __restrict__ env_nodes, const float* __restrict__ gamma_tp,
                 const half_t* __restrict__ W1F, const float* __restrict__ b1,
                 const half_t* __restrict__ W2F, const float* __restrict__ b2,
                 const half_t* __restrict__ Weq0F, const float* __restrict__ beq0,
                 const half_t* __restrict__ Weq1F, const half_t* __restrict__ Weq2F,
                 const float* __restrict__ g_eq,
                 const int* __restrict__ edge_index, const int* __restrict__ active_edges,
                 const float* __restrict__ w3j, float* __restrict__ out_s,
                 float* __restrict__ out_e) {
  __shared__ __align__(16) half_t stp[48 * 16 * 32];   // [kk-3][e][u^((e&3)*8)]; later tmp/sout f32
  __shared__ __align__(16) half_t ssc[16 * SSC_P];
  __shared__ __align__(16) half_t shh[16 * SSC_P];
  __shared__ float sg[16];
  __shared__ int snode[16];
  __shared__ int sact[16];
  const int t = threadIdx.x;
  const int e0 = blockIdx.x * 16;
  const float cc = updc[0];
  const float co = rsqrtf(cc * cc + 1.f);
  const float cn = cc * co;

  if (t < 16) {
    snode[t] = edge_index[e0 + t];
    sact[t] = active_edges[e0 + t];
    sg[t] = g_eq[e0 + t];
  }
  {
    int e = t >> 5, j = t & 31;
    ssc[e * SSC_P + 96 + j] = (half_t)cond[(size_t)(e0 + e) * 32 + j];
  }
  __syncthreads();

  // ---------- Phase 1: sparse-literal TP + SO3-LN (one edge/thread) ----------
  {
    const int eg = t >> 5, u = t & 31;
    const float* arow = equiv + (size_t)(e0 + eg) * 288 + u * 9;
    const float* brow = env_nodes + (size_t)snode[eg] * 288 + u * 9;
    float a0 = arow[0], b0 = brow[0];
    float A1[3] = {arow[1], arow[2], arow[3]};
    float A2[5] = {arow[4], arow[5], arow[6], arow[7], arow[8]};
    float B1[3] = {brow[1], brow[2], brow[3]};
    float B2[5] = {brow[4], brow[5], brow[6], brow[7], brow[8]};
    float o[51];
    o[0] = a0 * b0;
    o[1] = C3f * (A1[0]*B1[0] + A1[1]*B1[1] + A1[2]*B1[2]);
    o[2] = C5f * (A2[0]*B2[0] + A2[1]*B2[1] + A2[2]*B2[2] + A2[3]*B2[3] + A2[4]*B2[4]);
    o[3] = a0 * B1[0]; o[4] = a0 * B1[1]; o[5] = a0 * B1[2];
    o[6] = A1[0] * b0; o[7] = A1[1] * b0; o[8] = A1[2] * b0;
    // block 5 = (1,1,1): table-loaded (sign not analytically pinned; see STATE)
    o[9] = o[10] = o[11] = 0.f;
#pragma unroll
    for (int i = 0; i < 3; ++i)
#pragma unroll
      for (int j = 0; j < 3; ++j) {
        float p = A1[i] * B1[j];
#pragma unroll
        for (int k = 0; k < 3; ++k)
          o[9 + k] = fmaf(w3j[53 + (i * 3 + j) * 3 + k], p, o[9 + k]);
      }
    o[12] = S3f * (C10f*(A1[1]*B2[1] + A1[2]*B2[0]) - C30f*A1[0]*B2[2] - C10f*A1[0]*B2[4]);
    o[13] = S3f * (C10f*(A1[0]*B2[1] + A1[2]*B2[3]) + C30x2*A1[1]*B2[2]);
    o[14] = S3f * (C10f*(A1[0]*B2[0] + A1[1]*B2[3] + A1[2]*B2[4]) - C30f*A1[2]*B2[2]);
    o[15] = S3f * (C10f*(A2[1]*B1[1] + A2[0]*B1[2]) - C30f*A2[2]*B1[0] - C10f*A2[4]*B1[0]);
    o[16] = S3f * (C10f*(A2[1]*B1[0] + A2[3]*B1[2]) + C30x2*A2[2]*B1[1]);
    o[17] = S3f * (C10f*(A2[0]*B1[0] + A2[3]*B1[1] + A2[4]*B1[2]) - C30f*A2[2]*B1[2]);
    // block 8 = (2,2,1): table-loaded (see STATE)
    o[18] = o[19] = o[20] = 0.f;
#pragma unroll
    for (int i = 0; i < 5; ++i)
#pragma unroll
      for (int j = 0; j < 5; ++j) {
        float p = A2[i] * B2[j];
#pragma unroll
        for (int k = 0; k < 3; ++k)
          o[18 + k] = fmaf(w3j[170 + (i * 5 + j) * 3 + k], p, o[18 + k]);
      }
    o[21] = a0 * B2[0]; o[22] = a0 * B2[1]; o[23] = a0 * B2[2]; o[24] = a0 * B2[3]; o[25] = a0 * B2[4];
    o[26] = S5f * C10f * (A1[2]*B1[0] + A1[0]*B1[2]);
    o[27] = S5f * C10f * (A1[0]*B1[1] + A1[1]*B1[0]);
    o[28] = S5f * (C30x2*A1[1]*B1[1] - C30f*(A1[0]*B1[0] + A1[2]*B1[2]));
    o[29] = S5f * C10f * (A1[1]*B1[2] + A1[2]*B1[1]);
    o[30] = S5f * C10f * (A1[2]*B1[2] - A1[0]*B1[0]);
    o[31] = S5f * (C30f*(A1[2]*B2[3] - A1[0]*B2[1]) - C30x2*A1[1]*B2[4]);
    o[32] = S5f * (C30f*(A1[0]*B2[0] - A1[1]*B2[3] + A1[2]*B2[4]) + C10f*A1[2]*B2[2]);
    o[33] = S5f * C10f * (A1[0]*B2[3] - A1[2]*B2[1]);
    o[34] = S5f * (C30f*(A1[1]*B2[1] - A1[2]*B2[0] + A1[0]*B2[4]) - C10f*A1[0]*B2[2]);
    o[35] = S5f * (C30x2*A1[1]*B2[0] - C30f*(A1[2]*B2[1] + A1[0]*B2[3]));
    o[36] = A2[0] * b0; o[37] = A2[1] * b0; o[38] = A2[2] * b0; o[39] = A2[3] * b0; o[40] = A2[4] * b0;
    // blocks 13,14: reference = hand * (-1)  (proven; see STATE)
    o[41] = S5n * (C30f*(A2[3]*B1[2] - A2[1]*B1[0]) - C30x2*A2[4]*B1[1]);
    o[42] = S5n * (C30f*(A2[0]*B1[0] - A2[3]*B1[1] + A2[4]*B1[2]) + C10f*A2[2]*B1[2]);
    o[43] = S5n * C10f * (A2[3]*B1[0] - A2[1]*B1[2]);
    o[44] = S5n * (C30f*(A2[1]*B1[1] - A2[0]*B1[2] + A2[4]*B1[0]) - C10f*A2[2]*B1[0]);
    o[45] = S5n * (C30x2*A2[0]*B1[1] - C30f*(A2[1]*B1[2] + A2[3]*B1[0]));
    o[46] = S5n * (A235*(A2[0]*B2[2] + A2[2]*B2[0]) - B370*(A2[1]*B2[3] + A2[3]*B2[1]));
    o[47] = S5n * (-B370*(A2[0]*B2[3] + A2[3]*B2[0]) - C70f*(A2[1]*B2[2] + A2[2]*B2[1]) + B370*(A2[1]*B2[4] + A2[4]*B2[1]));
    o[48] = S5n * (A235*(A2[0]*B2[0] - A2[2]*B2[2] + A2[4]*B2[4]) - C70f*(A2[1]*B2[1] + A2[3]*B2[3]));
    o[49] = S5n * (-B370*(A2[0]*B2[1] + A2[1]*B2[0]) - C70f*(A2[3]*B2[2] + A2[2]*B2[3]) - B370*(A2[3]*B2[4] + A2[4]*B2[3]));
    o[50] = S5n * (B370*(A2[1]*B2[1] - A2[3]*B2[3]) + A235*(A2[2]*B2[4] + A2[4]*B2[2]));

    // LN: scalar blocks 0..2 -> ssc[e][u*3+b]
#pragma unroll
    for (int b = 0; b < 3; ++b) {
      float x = o[b];
      float s = x, q = x * x;
#pragma unroll
      for (int off = 16; off; off >>= 1) { s += __shfl_xor(s, off); q += __shfl_xor(q, off); }
      float mean = s * (1.f / 32.f);
      float var = q * (1.f / 32.f) - mean * mean;
      ssc[eg * SSC_P + u * 3 + b] = (half_t)((x - mean) * rsqrtf(var + 1e-6f) * gamma_tp[b * 32 + u]);
    }
    // LN: vector blocks -> stp[(kk-3)][e][u ^ ((e&3)*8)]
    const int offs[12] = {3, 6, 9, 12, 15, 18, 21, 26, 31, 36, 41, 46};
    const int d3s[12]  = {3, 3, 3, 3, 3, 3, 5, 5, 5, 5, 5, 5};
    const int uswz = u ^ ((eg & 3) << 3);
#pragma unroll
    for (int bb = 0; bb < 12; ++bb) {
      float q = 0.f;
#pragma unroll
      for (int k = 0; k < d3s[bb]; ++k) { float x = o[offs[bb] + k]; q += x * x; }
#pragma unroll
      for (int off = 16; off; off >>= 1) q += __shfl_xor(q, off);
      float scale = rsqrtf(q / (32.f * d3s[bb]) + 1e-6f) * gamma_tp[(bb + 3) * 32 + u];
#pragma unroll
      for (int k = 0; k < d3s[bb]; ++k)
        stp[((offs[bb] + k - 3) * 16 + eg) * 32 + uswz] = (half_t)(o[offs[bb] + k] * scale);
    }
  }
  __syncthreads();

  const int l = t & 63, wave = t >> 6;
  const int g = l >> 4, c = l & 15;
  f4 mlp2acc;

  // ---------- Phase 2: MLP layer 1 (MFMA), C[16e][128] ----------
  {
    const int nt = wave;
    float bn = b1[nt * 16 + c];
    f4 acc = {bn, bn, bn, bn};
#pragma unroll
    for (int ks = 0; ks < 4; ++ks) {
      h8 a = *(const h8*)&ssc[c * SSC_P + ks * 32 + g * 8];
      h8 b = *(const h8*)&W1F[(((nt * 4 + ks) * 64) + l) * 8];
      acc = __builtin_amdgcn_mfma_f32_16x16x32_f16(a, b, acc, 0, 0, 0);
    }
#pragma unroll
    for (int i = 0; i < 4; ++i) {
      float x = acc[i];
      shh[(4 * g + i) * SSC_P + nt * 16 + c] = (half_t)(x / (1.f + expf(-x)));
    }
  }
  __syncthreads();

  // ---------- Phase 3: MLP layer 2 (MFMA), result kept in registers ----------
  {
    const int nt = wave;
    float bn = b2[nt * 16 + c];
    f4 acc = {bn, bn, bn, bn};
#pragma unroll
    for (int ks = 0; ks < 4; ++ks) {
      h8 a = *(const h8*)&shh[c * SSC_P + ks * 32 + g * 8];
      h8 b = *(const h8*)&W2F[(((nt * 4 + ks) * 64) + l) * 8];
      acc = __builtin_amdgcn_mfma_f32_16x16x32_f16(a, b, acc, 0, 0, 0);
    }
    mlp2acc = acc;
  }

  // ---------- Phase 4: eq GEMMs (MFMA): 18 tiles over 8 waves ----------
  f4 accT[3];
  int nTiles = 0;
  for (int T = wave; T < 18; T += 8, ++nTiles) {
    f4 acc;
    if (T < 2) {
      const int nt = T;
      float bv = beq0[nt * 16 + c];
      acc = (f4){bv, bv, bv, bv};
#pragma unroll
      for (int ks = 0; ks < 3; ++ks) {
        h8 a = *(const h8*)&ssc[c * SSC_P + ks * 32 + g * 8];
        h8 b = *(const h8*)&Weq0F[(((nt * 3 + ks) * 64) + l) * 8];
        acc = __builtin_amdgcn_mfma_f32_16x16x32_f16(a, b, acc, 0, 0, 0);
      }
    } else if (T < 8) {
      const int idx = T - 2, Mt = idx >> 1, nt = idx & 1;
      const int row = Mt * 16 + c;
      const int e = row / 3, m = row - e * 3;
      const int gx = (g ^ (e & 3)) * 8;
      acc = (f4){0.f, 0.f, 0.f, 0.f};
#pragma unroll
      for (int ks = 0; ks < 6; ++ks) {
        int kk = ks * 3 + m;
        h8 a = *(const h8*)&stp[(kk * 16 + e) * 32 + gx];
        h8 b = *(const h8*)&Weq1F[(((nt * 6 + ks) * 64) + l) * 8];
        acc = __builtin_amdgcn_mfma_f32_16x16x32_f16(a, b, acc, 0, 0, 0);
      }
    } else {
      const int idx = T - 8, Mt = idx >> 1, nt = idx & 1;
      const int row = Mt * 16 + c;
      const int e = row / 5, m = row - e * 5;
      const int gx = (g ^ (e & 3)) * 8;
      acc = (f4){0.f, 0.f, 0.f, 0.f};
#pragma unroll
      for (int ks = 0; ks < 6; ++ks) {
        int kk = 18 + ks * 5 + m;
        h8 a = *(const h8*)&stp[(kk * 16 + e) * 32 + gx];
        h8 b = *(const h8*)&Weq2F[(((nt * 6 + ks) * 64) + l) * 8];
        acc = __builtin_amdgcn_mfma_f32_16x16x32_f16(a, b, acc, 0, 0, 0);
      }
    }
    accT[nTiles] = acc;
  }
  __syncthreads();

  // ---------- Phase 5: scatter eq results + MLP results to LDS ----------
  {
    float* tmp  = reinterpret_cast<float*>(&stp[0]);   // [16e][288] f32
    float* sout = tmp + 4608;                          // [16e][128] f32
    int slot = 0;
    for (int T = wave; T < 18; T += 8, ++slot) {
      f4 acc = accT[slot];
      int Mt, nt, type;
      if (T < 2)      { type = 0; Mt = 0; nt = T; }
      else if (T < 8) { type = 1; Mt = (T - 2) >> 1; nt = (T - 2) & 1; }
      else            { type = 2; Mt = (T - 8) >> 1; nt = (T - 8) & 1; }
      const int v = nt * 16 + c;
#pragma unroll
      for (int i = 0; i < 4; ++i) {
        int row = Mt * 16 + 4 * g + i;
        int e, off;
        if (type == 0)      { e = row; off = 0; }
        else if (type == 1) { e = row / 3; off = 1 + (row - e * 3); }
        else                { e = row / 5; off = 4 + (row - e * 5); }
        tmp[e * 288 + v * 9 + off] = cn * sg[e] * acc[i];
      }
    }
    {
      const int nt = wave;
#pragma unroll
      for (int i = 0; i < 4; ++i)
        sout[(4 * g + i) * 128 + nt * 16 + c] = cn * mlp2acc[i];
    }
  }
  __syncthreads();

  // ---------- Phase 6: coalesced residual + writes for BOTH outputs ----------
  {
    const float* tmp  = reinterpret_cast<const float*>(&stp[0]);
    const float* sout = tmp + 4608;
    const float4* tmp4 = (const float4*)tmp;
    for (int i = t; i < 16 * 72; i += 512) {
      int e = i / 72, q = i - e * 72;
      size_t r = (size_t)sact[e];
      const float4 ev = *(const float4*)&equiv[r * 288 + q * 4];
      float4 tv = tmp4[i];
      float4 ov;
      ov.x = co * ev.x + tv.x; ov.y = co * ev.y + tv.y;
      ov.z = co * ev.z + tv.z; ov.w = co * ev.w + tv.w;
      *(float4*)&out_e[r * 288 + q * 4] = ov;
    }
    for (int i = t; i < 16 * 128; i += 512) {
      int e = i >> 7, n = i & 127;
      size_t r = (size_t)sact[e];
      out_s[r * 128 + n] = co * scalar[r * 128 + n] + sout[i];
    }
  }
}

extern "C" void kernel_launch(void* const* d_in, const int* in_sizes, int n_in,
                              void* d_out, int out_size, void* d_ws, size_t ws_size,
                              hipStream_t stream) {
  const float* scalar     = (const float*)d_in[0];
  const float* equiv      = (const float*)d_in[1];
  const float* cond       = (const float*)d_in[2];
  const float* updc       = (const float*)d_in[3];
  const float* W_env      = (const float*)d_in[4];
  const float* b_env0     = (const float*)d_in[5];
  const float* gamma_env  = (const float*)d_in[6];
  const float* Wg_env     = (const float*)d_in[7];
  const float* bg_env     = (const float*)d_in[8];
  const float* gamma_tp   = (const float*)d_in[9];
  const float* W1         = (const float*)d_in[10];
  const float* b1         = (const float*)d_in[11];
  const float* W2         = (const float*)d_in[12];
  const float* b2         = (const float*)d_in[13];
  const float* Weq0       = (const float*)d_in[14];
  const float* beq0       = (const float*)d_in[15];
  const float* Weq1       = (const float*)d_in[16];
  const float* Weq2       = (const float*)d_in[17];
  const float* Wg_eq      = (const float*)d_in[18];
  const float* bg_eq      = (const float*)d_in[19];
  const int* edge_index   = (const int*)d_in[20];
  const int* active_edges = (const int*)d_in[21];

  float* out_s = (float*)d_out;
  float* out_e = out_s + (size_t)E_EDGES * 128;

  // ws layout (16B-aligned sections)
  float* ws    = (float*)d_ws;
  float* env   = ws;                                  // N_NODES*288 f
  float* w3jt  = env + (size_t)N_NODES * 288;         // 640 f (615 used)
  float* diag  = w3jt + 640;                          // 16 f (reserved)
  half_t* W1F   = (half_t*)(diag + 16);               // 16384 h
  half_t* W2F   = W1F + 16384;                        // 16384 h
  half_t* Weq0F = W2F + 16384;                        // 3072 h
  half_t* Weq1F = Weq0F + 3072;                       // 6144 h
  half_t* Weq2F = Weq1F + 6144;                       // 6144 h
  int* counts  = (int*)(Weq2F + 6144);                // 8192 int (becomes cursor)
  int* offsets = counts + N_NODES;                    // 8193 int
  float* g_eq  = (float*)(offsets + N_NODES + 1);     // 65536 f
  // CSR scratch in the tail of d_out (overwritten by out_e AFTER env_build)
  float* g_env = out_s + ((size_t)E_EDGES * (128 + 288) - 131072);
  int* elist   = (int*)(g_env + 65536);

  hipMemsetAsync(counts, 0, N_NODES * sizeof(int), stream);
  gen_w3j<<<15, 128, 0, stream>>>(w3jt);
  prep_weights<<<48, 256, 0, stream>>>(W1, W2, Weq0, Weq1, Weq2,
                                       W1F, W2F, Weq0F, Weq1F, Weq2F);
  gate_count<<<E_EDGES / 8, 256, 0, stream>>>(scalar, cond, Wg_env, bg_env, Wg_eq, bg_eq,
                                              edge_index, g_env, g_eq, counts);
  csr_scan<<<1, 256, 0, stream>>>(counts, offsets);
  csr_fill<<<E_EDGES / 256, 256, 0, stream>>>(edge_index, counts, elist);
  env_build<<<N_NODES, 128, 0, stream>>>(equiv, g_env, elist, offsets,
                                         W_env, b_env0, gamma_env, env);
  edge_update<<<E_EDGES / 16, 512, 0, stream>>>(scalar, equiv, cond, updc, env, gamma_tp,
                                                W1F, b1, W2F, b2, Weq0F, beq0, Weq1F, Weq2F,
                                                g_eq, edge_index, active_edges,
                                                w3jt, out_s, out_e);
}